// Round 4
// baseline (955.205 us; speedup 1.0000x reference)
//
#include <hip/hip_runtime.h>
#include <hip/hip_bf16.h>

#define DIMS 64
#define NBUCKETS 32

// ---------------------------------------------------------------------------
// Kernel A: XWh = bf16(X @ W)  (workspace)  and  out = X @ W1 (fp32 residual)
// 64-row tile, W/W1/X^T in LDS, 4x4x2 register tile. (unchanged)
// ---------------------------------------------------------------------------
__global__ __launch_bounds__(256) void gcn_gemm2(
    const float* __restrict__ X, const float* __restrict__ W,
    const float* __restrict__ W1, __hip_bfloat16* __restrict__ XWh,
    float* __restrict__ out, int N)
{
    __shared__ float Ws[64 * 64];
    __shared__ float W1s[64 * 64];
    __shared__ float Xs[64 * 68];

    const int t = threadIdx.x;

    for (int i = t; i < 1024; i += 256) {
        reinterpret_cast<float4*>(Ws)[i]  = reinterpret_cast<const float4*>(W)[i];
        reinterpret_cast<float4*>(W1s)[i] = reinterpret_cast<const float4*>(W1)[i];
    }

    const int row0 = blockIdx.x * 64;

    for (int i = t; i < 1024; i += 256) {
        const int r  = i >> 4;
        const int k4 = (i & 15) * 4;
        const int row = row0 + r;
        float4 v = make_float4(0.f, 0.f, 0.f, 0.f);
        if (row < N)
            v = reinterpret_cast<const float4*>(X)[(size_t)row * 16 + (i & 15)];
        Xs[(k4 + 0) * 68 + r] = v.x;
        Xs[(k4 + 1) * 68 + r] = v.y;
        Xs[(k4 + 2) * 68 + r] = v.z;
        Xs[(k4 + 3) * 68 + r] = v.w;
    }
    __syncthreads();

    const int dg = t & 15;
    const int rg = t >> 4;

    float4 acc[4];
    float4 acc1[4];
    #pragma unroll
    for (int r = 0; r < 4; ++r) {
        acc[r]  = make_float4(0.f, 0.f, 0.f, 0.f);
        acc1[r] = make_float4(0.f, 0.f, 0.f, 0.f);
    }

    #pragma unroll 4
    for (int k = 0; k < 64; ++k) {
        const float4 x4 = *reinterpret_cast<const float4*>(&Xs[k * 68 + rg * 4]);
        const float4 w  = *reinterpret_cast<const float4*>(&Ws[k * 64 + dg * 4]);
        const float4 w1 = *reinterpret_cast<const float4*>(&W1s[k * 64 + dg * 4]);
        const float xr[4] = {x4.x, x4.y, x4.z, x4.w};
        #pragma unroll
        for (int r = 0; r < 4; ++r) {
            acc[r].x  += xr[r] * w.x;  acc[r].y  += xr[r] * w.y;
            acc[r].z  += xr[r] * w.z;  acc[r].w  += xr[r] * w.w;
            acc1[r].x += xr[r] * w1.x; acc1[r].y += xr[r] * w1.y;
            acc1[r].z += xr[r] * w1.z; acc1[r].w += xr[r] * w1.w;
        }
    }

    #pragma unroll
    for (int r = 0; r < 4; ++r) {
        const int row = row0 + rg * 4 + r;
        if (row < N) {
            reinterpret_cast<float4*>(out)[(size_t)row * 16 + dg] = acc1[r];
            uint2 pk;
            __hip_bfloat16* ph = reinterpret_cast<__hip_bfloat16*>(&pk);
            ph[0] = __float2bfloat16(acc[r].x);
            ph[1] = __float2bfloat16(acc[r].y);
            ph[2] = __float2bfloat16(acc[r].z);
            ph[3] = __float2bfloat16(acc[r].w);
            reinterpret_cast<uint2*>(XWh)[(size_t)row * 16 + dg] = pk;
        }
    }
}

// ---------------------------------------------------------------------------
// Kernel R: row_ptr from sorted rows; also zeroes the sentinel XWh row (row N)
// and the bucket counters used by the degree-balancing pipeline.
// ---------------------------------------------------------------------------
__global__ __launch_bounds__(256) void build_row_ptr(
    const int* __restrict__ rows, int* __restrict__ ptr,
    __hip_bfloat16* __restrict__ XWh, int* __restrict__ cnt, int E, int N)
{
    const int e = blockIdx.x * 256 + threadIdx.x;
    if (blockIdx.x == 0) {
        const int t = threadIdx.x;
        if (t < 32)
            reinterpret_cast<uint32_t*>(XWh + (size_t)N * DIMS)[t] = 0u;  // sentinel row = 0
        else if (t < 32 + NBUCKETS)
            cnt[t - 32] = 0;
    }
    if (e >= E) return;
    const int r1 = rows[e];
    const int r0 = (e == 0) ? -1 : rows[e - 1];
    for (int r = r0 + 1; r <= r1; ++r) ptr[r] = e;
    if (e == E - 1) {
        for (int r = r1 + 1; r <= N; ++r) ptr[r] = E;
    }
}

// ---------------------------------------------------------------------------
// Degree-balancing pipeline: count -> scan -> scatter. perm groups rows of
// near-equal degree so the 8 rows in a csr wave have matched trip counts.
// ---------------------------------------------------------------------------
__global__ __launch_bounds__(256) void deg_count(
    const int* __restrict__ ptr, int* __restrict__ cnt, int N)
{
    const int r = blockIdx.x * 256 + threadIdx.x;
    if (r >= N) return;
    const int d = ptr[r + 1] - ptr[r];
    const int b = (d >> 1) < (NBUCKETS - 1) ? (d >> 1) : (NBUCKETS - 1);
    atomicAdd(&cnt[b], 1);
}

__global__ void deg_scan(int* __restrict__ cnt)
{
    // single thread: exclusive scan of 32 counters in place
    if (threadIdx.x == 0 && blockIdx.x == 0) {
        int run = 0;
        for (int b = 0; b < NBUCKETS; ++b) {
            const int c = cnt[b];
            cnt[b] = run;
            run += c;
        }
    }
}

__global__ __launch_bounds__(256) void deg_scatter(
    const int* __restrict__ ptr, int* __restrict__ cnt,
    int* __restrict__ perm, int N)
{
    const int r = blockIdx.x * 256 + threadIdx.x;
    if (r >= N) return;
    const int d = ptr[r + 1] - ptr[r];
    const int b = (d >> 1) < (NBUCKETS - 1) ? (d >> 1) : (NBUCKETS - 1);
    const int idx = atomicAdd(&cnt[b], 1);
    perm[idx] = r;
}

// ---------------------------------------------------------------------------
// Kernel B: CSR row-centric aggregation, degree-balanced + branchless.
// One wave = 8 rows (via perm); 8-lane group per row; lane d = dims [8d,8d+8)
// as bf16x8 (16 B dwordx4). Inactive slots gather the sentinel zero row ->
// unconditional loads, no masking of the accumulate, no exec juggling.
// ---------------------------------------------------------------------------
__global__ __launch_bounds__(256) void gcn_csr(
    const __hip_bfloat16* __restrict__ XWh, const float* __restrict__ dd1,
    const int* __restrict__ ptr, const int* __restrict__ cols,
    const int* __restrict__ perm, float* __restrict__ out, int N, int E)
{
    const int t    = blockIdx.x * 256 + threadIdx.x;
    const int wave = t >> 6;
    const int lane = threadIdx.x & 63;
    const int g    = lane >> 3;     // group 0..7  -> row slot
    const int d    = lane & 7;      // dim block   -> dims [8d, 8d+8)

    const int wrow = wave * 8 + g;
    int row = 0, p0 = 0, p1 = 0;
    if (wrow < N) { row = perm[wrow]; p0 = ptr[row]; p1 = ptr[row + 1]; }

    float2 acc[4];
    #pragma unroll
    for (int k = 0; k < 4; ++k) acc[k] = make_float2(0.f, 0.f);

    for (int e = p0; __any(e < p1); e += 4) {
        uint4 raw[4];
        #pragma unroll
        for (int j = 0; j < 4; ++j) {
            const int ee = e + j;
            const int es = (ee < E) ? ee : (E - 1);      // safe index read
            const int cl = cols[es];
            const int c  = (ee < p1) ? cl : N;           // sentinel -> zeros
            raw[j] = *reinterpret_cast<const uint4*>(
                XWh + (((size_t)c) << 6) + (d << 3));
        }
        #pragma unroll
        for (int j = 0; j < 4; ++j) {
            const uint32_t w0 = raw[j].x, w1 = raw[j].y, w2 = raw[j].z, w3 = raw[j].w;
            acc[0].x += __uint_as_float(w0 << 16);
            acc[0].y += __uint_as_float(w0 & 0xffff0000u);
            acc[1].x += __uint_as_float(w1 << 16);
            acc[1].y += __uint_as_float(w1 & 0xffff0000u);
            acc[2].x += __uint_as_float(w2 << 16);
            acc[2].y += __uint_as_float(w2 & 0xffff0000u);
            acc[3].x += __uint_as_float(w3 << 16);
            acc[3].y += __uint_as_float(w3 & 0xffff0000u);
        }
    }

    if (wrow < N) {
        const float s = 1.0f / dd1[row];
        float4* po = reinterpret_cast<float4*>(out + (size_t)row * DIMS + d * 8);
        float4 o0 = po[0];
        float4 o1 = po[1];
        o0.x += acc[0].x * s;  o0.y += acc[0].y * s;
        o0.z += acc[1].x * s;  o0.w += acc[1].y * s;
        o1.x += acc[2].x * s;  o1.y += acc[2].y * s;
        o1.z += acc[3].x * s;  o1.w += acc[3].y * s;
        po[0] = o0;
        po[1] = o1;
    }
}

// ---------------------------------------------------------------------------
extern "C" void kernel_launch(void* const* d_in, const int* in_sizes, int n_in,
                              void* d_out, int out_size, void* d_ws, size_t ws_size,
                              hipStream_t stream) {
    const float* X   = (const float*)d_in[0];
    const float* W   = (const float*)d_in[1];
    const float* W1  = (const float*)d_in[2];
    const float* dd1 = (const float*)d_in[3];
    const int* rows  = (const int*)d_in[4];
    const int* cols  = (const int*)d_in[5];

    const int N = in_sizes[3];
    const int E = in_sizes[4];

    // ws layout: XWh (N+1 rows incl. sentinel) | row_ptr | perm | cnt
    char* wsp = (char*)d_ws;
    __hip_bfloat16* XWh = (__hip_bfloat16*)wsp;
    size_t off = (((size_t)(N + 1) * DIMS * sizeof(__hip_bfloat16)) + 255) & ~(size_t)255;
    int* row_ptr = (int*)(wsp + off);
    off += (((size_t)(N + 1) * sizeof(int)) + 255) & ~(size_t)255;
    int* perm = (int*)(wsp + off);
    off += (((size_t)N * sizeof(int)) + 255) & ~(size_t)255;
    int* cnt = (int*)(wsp + off);

    float* out = (float*)d_out;

    const int gridN = (N + 255) / 256;

    // R: row_ptr + zero sentinel XWh row + zero bucket counters
    hipLaunchKernelGGL(build_row_ptr, dim3((E + 255) / 256), dim3(256), 0, stream,
                       rows, row_ptr, XWh, cnt, E, N);

    // A: XWh = bf16(X@W), out = X@W1
    hipLaunchKernelGGL(gcn_gemm2, dim3((N + 63) / 64), dim3(256), 0, stream,
                       X, W, W1, XWh, out, N);

    // Degree-balancing: count -> scan -> scatter into perm
    hipLaunchKernelGGL(deg_count, dim3(gridN), dim3(256), 0, stream, row_ptr, cnt, N);
    hipLaunchKernelGGL(deg_scan, dim3(1), dim3(64), 0, stream, cnt);
    hipLaunchKernelGGL(deg_scatter, dim3(gridN), dim3(256), 0, stream, row_ptr, cnt, perm, N);

    // B: out[row] += (sum_{e in row} XWh[cols[e]]) / dd1[row]
    const int waves  = (N + 7) / 8;
    const int blocks = (waves + 3) / 4;
    hipLaunchKernelGGL(gcn_csr, dim3(blocks), dim3(256), 0, stream,
                       XWh, dd1, row_ptr, cols, perm, out, N, E);
}

// Round 5
// 145.700 us; speedup vs baseline: 6.5560x; 6.5560x over previous
//
#include <hip/hip_runtime.h>
#include <hip/hip_bf16.h>

#define DIMS 64

// ---------------------------------------------------------------------------
// Kernel A: XWh = bf16(X @ W)  (workspace)  and  out = X @ W1 (fp32 residual)
// 64-row tile, W/W1/X^T in LDS, 4x4x2 register tile. (unchanged, ~15 us,
// HBM-bound: ~90 MB traffic)
// ---------------------------------------------------------------------------
__global__ __launch_bounds__(256) void gcn_gemm2(
    const float* __restrict__ X, const float* __restrict__ W,
    const float* __restrict__ W1, __hip_bfloat16* __restrict__ XWh,
    float* __restrict__ out, int N)
{
    __shared__ float Ws[64 * 64];
    __shared__ float W1s[64 * 64];
    __shared__ float Xs[64 * 68];

    const int t = threadIdx.x;

    for (int i = t; i < 1024; i += 256) {
        reinterpret_cast<float4*>(Ws)[i]  = reinterpret_cast<const float4*>(W)[i];
        reinterpret_cast<float4*>(W1s)[i] = reinterpret_cast<const float4*>(W1)[i];
    }

    const int row0 = blockIdx.x * 64;

    for (int i = t; i < 1024; i += 256) {
        const int r  = i >> 4;
        const int k4 = (i & 15) * 4;
        const int row = row0 + r;
        float4 v = make_float4(0.f, 0.f, 0.f, 0.f);
        if (row < N)
            v = reinterpret_cast<const float4*>(X)[(size_t)row * 16 + (i & 15)];
        Xs[(k4 + 0) * 68 + r] = v.x;
        Xs[(k4 + 1) * 68 + r] = v.y;
        Xs[(k4 + 2) * 68 + r] = v.z;
        Xs[(k4 + 3) * 68 + r] = v.w;
    }
    __syncthreads();

    const int dg = t & 15;
    const int rg = t >> 4;

    float4 acc[4];
    float4 acc1[4];
    #pragma unroll
    for (int r = 0; r < 4; ++r) {
        acc[r]  = make_float4(0.f, 0.f, 0.f, 0.f);
        acc1[r] = make_float4(0.f, 0.f, 0.f, 0.f);
    }

    #pragma unroll 4
    for (int k = 0; k < 64; ++k) {
        const float4 x4 = *reinterpret_cast<const float4*>(&Xs[k * 68 + rg * 4]);
        const float4 w  = *reinterpret_cast<const float4*>(&Ws[k * 64 + dg * 4]);
        const float4 w1 = *reinterpret_cast<const float4*>(&W1s[k * 64 + dg * 4]);
        const float xr[4] = {x4.x, x4.y, x4.z, x4.w};
        #pragma unroll
        for (int r = 0; r < 4; ++r) {
            acc[r].x  += xr[r] * w.x;  acc[r].y  += xr[r] * w.y;
            acc[r].z  += xr[r] * w.z;  acc[r].w  += xr[r] * w.w;
            acc1[r].x += xr[r] * w1.x; acc1[r].y += xr[r] * w1.y;
            acc1[r].z += xr[r] * w1.z; acc1[r].w += xr[r] * w1.w;
        }
    }

    #pragma unroll
    for (int r = 0; r < 4; ++r) {
        const int row = row0 + rg * 4 + r;
        if (row < N) {
            reinterpret_cast<float4*>(out)[(size_t)row * 16 + dg] = acc1[r];
            uint2 pk;
            __hip_bfloat16* ph = reinterpret_cast<__hip_bfloat16*>(&pk);
            ph[0] = __float2bfloat16(acc[r].x);
            ph[1] = __float2bfloat16(acc[r].y);
            ph[2] = __float2bfloat16(acc[r].z);
            ph[3] = __float2bfloat16(acc[r].w);
            reinterpret_cast<uint2*>(XWh)[(size_t)row * 16 + dg] = pk;
        }
    }
}

// ---------------------------------------------------------------------------
// Kernel R: row_ptr from sorted rows; also zeroes the sentinel XWh row (row N).
// ---------------------------------------------------------------------------
__global__ __launch_bounds__(256) void build_row_ptr(
    const int* __restrict__ rows, int* __restrict__ ptr,
    __hip_bfloat16* __restrict__ XWh, int E, int N)
{
    const int e = blockIdx.x * 256 + threadIdx.x;
    if (blockIdx.x == 0 && threadIdx.x < 32)
        reinterpret_cast<uint32_t*>(XWh + (size_t)N * DIMS)[threadIdx.x] = 0u;
    if (e >= E) return;
    const int r1 = rows[e];
    const int r0 = (e == 0) ? -1 : rows[e - 1];
    for (int r = r0 + 1; r <= r1; ++r) ptr[r] = e;
    if (e == E - 1) {
        for (int r = r1 + 1; r <= N; ++r) ptr[r] = E;
    }
}

// ---------------------------------------------------------------------------
// Kernel B: CSR row-centric aggregation, branchless via sentinel zero row.
// One wave = 8 rows; 8-lane group per row; lane d = dims [8d,8d+8) as bf16x8
// (16 B dwordx4 gather: one wave instruction = 8 edges' row-slices).
// 8-deep edge batch per group -> 64 gathers in flight per wave.
// No atomics: group-private fp32 acc, one RMW on top of the X@W1 residual.
// ---------------------------------------------------------------------------
#define BATCH 8

__global__ __launch_bounds__(256) void gcn_csr(
    const __hip_bfloat16* __restrict__ XWh, const float* __restrict__ dd1,
    const int* __restrict__ ptr, const int* __restrict__ cols,
    float* __restrict__ out, int N, int E)
{
    const int t    = blockIdx.x * 256 + threadIdx.x;
    const int wave = t >> 6;
    const int lane = threadIdx.x & 63;
    const int g    = lane >> 3;     // group 0..7  -> row
    const int d    = lane & 7;      // dim block   -> dims [8d, 8d+8)

    const int row = wave * 8 + g;
    int p0 = 0, p1 = 0;
    if (row < N) { p0 = ptr[row]; p1 = ptr[row + 1]; }

    float2 acc[4];
    #pragma unroll
    for (int k = 0; k < 4; ++k) acc[k] = make_float2(0.f, 0.f);

    for (int e = p0; __any(e < p1); e += BATCH) {
        uint4 raw[BATCH];
        #pragma unroll
        for (int j = 0; j < BATCH; ++j) {
            const int ee = e + j;
            const int es = (ee < E) ? ee : (E - 1);      // safe index read
            const int cl = cols[es];
            const int c  = (ee < p1) ? cl : N;           // sentinel -> zeros
            raw[j] = *reinterpret_cast<const uint4*>(
                XWh + (((size_t)c) << 6) + (d << 3));
        }
        #pragma unroll
        for (int j = 0; j < BATCH; ++j) {
            const uint32_t w0 = raw[j].x, w1 = raw[j].y, w2 = raw[j].z, w3 = raw[j].w;
            acc[0].x += __uint_as_float(w0 << 16);
            acc[0].y += __uint_as_float(w0 & 0xffff0000u);
            acc[1].x += __uint_as_float(w1 << 16);
            acc[1].y += __uint_as_float(w1 & 0xffff0000u);
            acc[2].x += __uint_as_float(w2 << 16);
            acc[2].y += __uint_as_float(w2 & 0xffff0000u);
            acc[3].x += __uint_as_float(w3 << 16);
            acc[3].y += __uint_as_float(w3 & 0xffff0000u);
        }
    }

    if (row < N) {
        const float s = 1.0f / dd1[row];
        float4* po = reinterpret_cast<float4*>(out + (size_t)row * DIMS + d * 8);
        float4 o0 = po[0];
        float4 o1 = po[1];
        o0.x += acc[0].x * s;  o0.y += acc[0].y * s;
        o0.z += acc[1].x * s;  o0.w += acc[1].y * s;
        o1.x += acc[2].x * s;  o1.y += acc[2].y * s;
        o1.z += acc[3].x * s;  o1.w += acc[3].y * s;
        po[0] = o0;
        po[1] = o1;
    }
}

// ---------------------------------------------------------------------------
extern "C" void kernel_launch(void* const* d_in, const int* in_sizes, int n_in,
                              void* d_out, int out_size, void* d_ws, size_t ws_size,
                              hipStream_t stream) {
    const float* X   = (const float*)d_in[0];
    const float* W   = (const float*)d_in[1];
    const float* W1  = (const float*)d_in[2];
    const float* dd1 = (const float*)d_in[3];
    const int* rows  = (const int*)d_in[4];
    const int* cols  = (const int*)d_in[5];

    const int N = in_sizes[3];
    const int E = in_sizes[4];

    // ws layout: XWh (N+1 rows incl. sentinel) | row_ptr
    char* wsp = (char*)d_ws;
    __hip_bfloat16* XWh = (__hip_bfloat16*)wsp;
    size_t off = (((size_t)(N + 1) * DIMS * sizeof(__hip_bfloat16)) + 255) & ~(size_t)255;
    int* row_ptr = (int*)(wsp + off);

    float* out = (float*)d_out;

    // R: row_ptr + zero sentinel XWh row
    hipLaunchKernelGGL(build_row_ptr, dim3((E + 255) / 256), dim3(256), 0, stream,
                       rows, row_ptr, XWh, E, N);

    // A: XWh = bf16(X@W), out = X@W1
    hipLaunchKernelGGL(gcn_gemm2, dim3((N + 63) / 64), dim3(256), 0, stream,
                       X, W, W1, XWh, out, N);

    // B: out[row] += (sum_{e in row} XWh[cols[e]]) / dd1[row]
    const int waves  = (N + 7) / 8;
    const int blocks = (waves + 3) / 4;
    hipLaunchKernelGGL(gcn_csr, dim3(blocks), dim3(256), 0, stream,
                       XWh, dd1, row_ptr, cols, out, N, E);
}